// Round 1
// baseline (7469.212 us; speedup 1.0000x reference)
//
#include <hip/hip_runtime.h>
#include <hip/hip_fp16.h>
#include <math.h>

#define HD   512
#define BB   256
#define TT   200
#define DIN  64
#define DOUT 64
#define NCLS 10
#define LIPC 0.909f
#define RPB  4            // batch rows per block (weight reads amortized 4x)

// d_ws layout: gs (fp32, (TT-1)*HD) then pair-packed half2 weights.
// W2[kp][col] = (W[2kp][col], W[2kp+1][col]) as one uint (half2).
#define GS_BYTES    407552
#define OFF2_WX     0              // 32 kp x 512
#define OFF2_WEMB   16384          // 512 kp x 512
#define OFF2_WF1    278528         // 256 kp x 512
#define OFF2_WF2    409600
#define OFF2_WOUT   540672
#define OFF2_WDEC   671744         // 256 kp x 64
#define NPACK       688128         // total uints

__device__ __forceinline__ float lipswish(float x) {
    return LIPC * x / (1.0f + expf(-x));
}

typedef _Float16 h2_t __attribute__((ext_vector_type(2)));

__device__ __forceinline__ float fdot2u(unsigned a, unsigned b, float c) {
    return __builtin_amdgcn_fdot2(__builtin_bit_cast(h2_t, a),
                                  __builtin_bit_cast(h2_t, b), c, false);
}

// pack adjacent-column fp32 activations into half2 LDS, row-interleaved
// layout dst[kp*4 + r]: thread j holds v for col j (row r); even lanes
// write pair (j, j+1).
__device__ __forceinline__ void pack4(float v, unsigned* dstH, int j, int r) {
    float other = __shfl_xor(v, 1, 64);
    if (!(j & 1)) {
        __half2 hp = __floats2half2_rn(v, other);
        dstH[((j >> 1) << 2) + r] = __builtin_bit_cast(unsigned, hp);
    }
}

// ---------------------------------------------------------------------------
// cvt: fp32 weights -> pair-packed half2. 1344 blocks x 512. (unchanged)
// ---------------------------------------------------------------------------
__global__ __launch_bounds__(512) void cvt_kernel(
    const float* __restrict__ W_X,  const float* __restrict__ W_emb,
    const float* __restrict__ Wf1,  const float* __restrict__ Wf2,
    const float* __restrict__ W_out, const float* __restrict__ W_dec,
    unsigned* __restrict__ dst)
{
    int bid = blockIdx.x;
    size_t e = ((size_t)bid << 9) + threadIdx.x;
    const float* src; size_t off2; int csh;
    if      (bid < 32)   { src = W_X;   off2 = OFF2_WX;   csh = 9; }
    else if (bid < 544)  { src = W_emb; off2 = OFF2_WEMB; csh = 9; }
    else if (bid < 800)  { src = Wf1;   off2 = OFF2_WF1;  csh = 9; }
    else if (bid < 1056) { src = Wf2;   off2 = OFF2_WF2;  csh = 9; }
    else if (bid < 1312) { src = W_out; off2 = OFF2_WOUT; csh = 9; }
    else                 { src = W_dec; off2 = OFF2_WDEC; csh = 6; }
    size_t e2 = e - off2;
    size_t kp = e2 >> csh;
    size_t c  = e2 & (((size_t)1 << csh) - 1);
    size_t C  = (size_t)1 << csh;
    __half2 hp = __floats2half2_rn(src[(2 * kp) * C + c], src[(2 * kp + 1) * C + c]);
    dst[e] = __builtin_bit_cast(unsigned, hp);
}

// ---------------------------------------------------------------------------
// fp32 partial matvec for g_kernel (unchanged)
// ---------------------------------------------------------------------------
template<int K>
__device__ __forceinline__ void mv_part(const float* __restrict__ W,
                                        const float* src, float* part, int j)
{
    const int g = j >> 7, c = j & 127;
    const int kpg = K >> 2;
    const int k0 = g * kpg;
    const float4* __restrict__ W4 = (const float4*)W;
    float4 acc; acc.x = acc.y = acc.z = acc.w = 0.f;
#pragma unroll 2
    for (int k = k0; k < k0 + kpg; k += 4) {
        float4 a  = *(const float4*)(src + k);
        float4 w0 = W4[(size_t)(k + 0) * 128 + c];
        float4 w1 = W4[(size_t)(k + 1) * 128 + c];
        float4 w2 = W4[(size_t)(k + 2) * 128 + c];
        float4 w3 = W4[(size_t)(k + 3) * 128 + c];
        acc.x = fmaf(a.x, w0.x, acc.x); acc.y = fmaf(a.x, w0.y, acc.y);
        acc.z = fmaf(a.x, w0.z, acc.z); acc.w = fmaf(a.x, w0.w, acc.w);
        acc.x = fmaf(a.y, w1.x, acc.x); acc.y = fmaf(a.y, w1.y, acc.y);
        acc.z = fmaf(a.y, w1.z, acc.z); acc.w = fmaf(a.y, w1.w, acc.w);
        acc.x = fmaf(a.z, w2.x, acc.x); acc.y = fmaf(a.z, w2.y, acc.y);
        acc.z = fmaf(a.z, w2.z, acc.z); acc.w = fmaf(a.z, w2.w, acc.w);
        acc.x = fmaf(a.w, w3.x, acc.x); acc.y = fmaf(a.w, w3.y, acc.y);
        acc.z = fmaf(a.w, w3.z, acc.z); acc.w = fmaf(a.w, w3.w, acc.w);
    }
    *(float4*)(part + g * HD + 4 * c) = acc;
}
#define MV_REDUCE4(bias, j) ((bias)[j] + part[j] + part[HD + (j)] + part[2 * HD + (j)] + part[3 * HD + (j)])

__global__ __launch_bounds__(512) void g_kernel(
    const float* __restrict__ times, const float* __restrict__ W_noise,
    const float* __restrict__ b_noise, const float* __restrict__ Wg1,
    const float* __restrict__ bg1, const float* __restrict__ Wg2,
    const float* __restrict__ bg2, float* __restrict__ gs)
{
    int t = blockIdx.x;
    int j = threadIdx.x;
    __shared__ float tt[HD];
    __shared__ float h[HD];
    __shared__ float part[4 * HD];
    float tv = times[t];
    tt[j] = tv * W_noise[j] + b_noise[j];
    __syncthreads();
    mv_part<HD>(Wg1, tt, part, j);
    __syncthreads();
    h[j] = lipswish(MV_REDUCE4(bg1, j));
    __syncthreads();
    mv_part<HD>(Wg2, h, part, j);
    __syncthreads();
    float dt = times[t + 1] - times[t];
    gs[t * HD + j] = MV_REDUCE4(bg2, j) * sqrtf(dt);
}

// ---------------------------------------------------------------------------
// 4-row dot2 matvec: 4 k-groups (g=j>>7) x 128 col-quads.
// Per kp: 1 ds_read_b128 (4 rows' act half2, broadcast) + 1 dwordx4
// (4 half2 weight cols) + 16 v_dot2_f32_f16 => 64 MACs.
// Weight bytes/MAC = 16B/64 = 0.25 (4x better than 1-row version).
// ---------------------------------------------------------------------------
template<int KP>
__device__ __forceinline__ void mv4(const unsigned* __restrict__ W2,
                                    const unsigned* actH,   // [kp*4 + r]
                                    float* part, int j)
{
    const int g  = j >> 7;            // k-group
    const int c4 = (j & 127) << 2;    // 4 output cols
    constexpr int kpg = KP / 4;
    const int kp0 = g * kpg;
    float a00 = 0.f, a01 = 0.f, a02 = 0.f, a03 = 0.f;
    float a10 = 0.f, a11 = 0.f, a12 = 0.f, a13 = 0.f;
    float a20 = 0.f, a21 = 0.f, a22 = 0.f, a23 = 0.f;
    float a30 = 0.f, a31 = 0.f, a32 = 0.f, a33 = 0.f;
#pragma unroll 4
    for (int kp = kp0; kp < kp0 + kpg; ++kp) {
        uint4 ap = *(const uint4*)(actH + (kp << 2));
        uint4 w  = *(const uint4*)(W2 + ((size_t)kp << 9) + c4);
        a00 = fdot2u(ap.x, w.x, a00); a01 = fdot2u(ap.x, w.y, a01);
        a02 = fdot2u(ap.x, w.z, a02); a03 = fdot2u(ap.x, w.w, a03);
        a10 = fdot2u(ap.y, w.x, a10); a11 = fdot2u(ap.y, w.y, a11);
        a12 = fdot2u(ap.y, w.z, a12); a13 = fdot2u(ap.y, w.w, a13);
        a20 = fdot2u(ap.z, w.x, a20); a21 = fdot2u(ap.z, w.y, a21);
        a22 = fdot2u(ap.z, w.z, a22); a23 = fdot2u(ap.z, w.w, a23);
        a30 = fdot2u(ap.w, w.x, a30); a31 = fdot2u(ap.w, w.y, a31);
        a32 = fdot2u(ap.w, w.z, a32); a33 = fdot2u(ap.w, w.w, a33);
    }
    float* pb = part + ((g << 2) << 9) + c4;   // part[(g*4+r)*512 + c4]
    *(float4*)(pb)            = make_float4(a00, a01, a02, a03);
    *(float4*)(pb + 1 * HD)   = make_float4(a10, a11, a12, a13);
    *(float4*)(pb + 2 * HD)   = make_float4(a20, a21, a22, a23);
    *(float4*)(pb + 3 * HD)   = make_float4(a30, a31, a32, a33);
}

// reduce 4 k-groups for (row r, col j)
__device__ __forceinline__ float red4(const float* part, const float* __restrict__ bias,
                                      int j, int r) {
    return bias[j] + ((part[(0 * 4 + r) * HD + j] + part[(1 * 4 + r) * HD + j])
                    + (part[(2 * 4 + r) * HD + j] + part[(3 * 4 + r) * HD + j]));
}

// ---------------------------------------------------------------------------
// 4-row dot2 decode (512 -> 64) + store.
// 2 k-groups (g=j>>8) x 4 rows x 64 cols. Act read broadcast per wave.
// ---------------------------------------------------------------------------
__device__ __forceinline__ void dec4(const unsigned* __restrict__ Wd2,
    const float* __restrict__ b_dec, const unsigned* yH, float* part,
    int j, int b0, int tout, float* __restrict__ out)
{
    const int g = j >> 8;           // 2 k-groups x 128 kp
    const int r = (j >> 6) & 3;     // wave-uniform
    const int c = j & 63;
    const int kp0 = g << 7;
    float a0 = 0.f, a1 = 0.f;
#pragma unroll 4
    for (int kp = kp0; kp < kp0 + 128; kp += 2) {
        unsigned p0 = yH[(kp << 2) + r];
        unsigned p1 = yH[((kp + 1) << 2) + r];
        a0 = fdot2u(p0, Wd2[(kp << 6) + c], a0);
        a1 = fdot2u(p1, Wd2[((kp + 1) << 6) + c], a1);
    }
    part[(g << 8) + (r << 6) + c] = a0 + a1;
    __syncthreads();
    if (j < 256) {
        int rr = j >> 6, cc = j & 63;
        float s = b_dec[cc] + part[(rr << 6) + cc] + part[256 + (rr << 6) + cc];
        out[((size_t)(b0 + rr) * TT + tout) * DOUT + cc] = s;
    }
    // caller's next barrier protects part reuse
}

// ---------------------------------------------------------------------------
// Batch-parallel SDE scan, 4 rows per block: grid = 64 blocks x 512 threads.
// Weight streams from L2 are shared by 4 batch rows.
// ---------------------------------------------------------------------------
__global__ __launch_bounds__(512) void scan_kernel(
    const float* __restrict__ coeffs,
    const float* __restrict__ times,
    const float* __restrict__ noise,
    const float* __restrict__ b_X,
    const float* __restrict__ b_emb,
    const float* __restrict__ bf1,
    const float* __restrict__ bf2,
    const float* __restrict__ b_out,
    const float* __restrict__ W_init, const float* __restrict__ b_init,
    const float* __restrict__ b_dec,
    const float* __restrict__ W_cls, const float* __restrict__ b_cls,
    const int* __restrict__ mask,
    const float* __restrict__ gs,
    const unsigned* __restrict__ W2,    // pair-packed half2 weights
    float* __restrict__ out)
{
    const int b0 = blockIdx.x * RPB;
    const int j  = threadIdx.x;

    const unsigned* __restrict__ W_X_2   = W2 + OFF2_WX;
    const unsigned* __restrict__ W_emb_2 = W2 + OFF2_WEMB;
    const unsigned* __restrict__ Wf1_2   = W2 + OFF2_WF1;
    const unsigned* __restrict__ Wf2_2   = W2 + OFF2_WF2;
    const unsigned* __restrict__ W_out_2 = W2 + OFF2_WOUT;
    const unsigned* __restrict__ W_dec_2 = W2 + OFF2_WDEC;

    __shared__ __align__(16) float    yF[RPB * HD];        // fp32 Euler state
    __shared__ __align__(16) unsigned catH[RPB * HD];      // [kp*4+r]: y kp 0..255 | xw kp 256..511
    __shared__ __align__(16) unsigned actAH[RPB * HD / 2]; // [kp*4+r]
    __shared__ __align__(16) unsigned actBH[RPB * HD / 2];
    __shared__ __align__(16) unsigned avecH[RPB * DIN / 2];
    __shared__ __align__(16) float    avecF[RPB * DIN];    // [k*4+r]
    __shared__ __align__(16) float    part[16 * HD];       // 32 KB partials
    __shared__ __align__(16) float    zfin[RPB * HD];
    __shared__ float    tl[TT];
    __shared__ int      lidx_s[RPB];

    if (j < TT) tl[j] = times[j];

    // ---- per-row lengths from mask (4 rows, 128 threads each) ----
    {
        int r = j >> 7, i = j & 127;
        int m = 0;
        for (int t2 = i; t2 < TT; t2 += 128) m += mask[(b0 + r) * TT + t2];
        part[j] = (float)m;
        __syncthreads();
        for (int s = 64; s > 0; s >>= 1) {
            if (i < s) part[j] += part[j + s];
            __syncthreads();
        }
        if (i == 0) lidx_s[r] = (int)part[r << 7] - 1;
        __syncthreads();
    }

    // ---- y0 = a0 @ W_init + b_init (fp32, one-time, 4 rows share W_init) ----
    if (j < RPB * DIN) {
        int k = j >> 2, r = j & 3;
        avecF[(k << 2) + r] = coeffs[(size_t)(b0 + r) * (TT - 1) * (4 * DIN) + k];
    }
    __syncthreads();
    {
        float acc0 = 0.f, acc1 = 0.f, acc2 = 0.f, acc3 = 0.f;
#pragma unroll 8
        for (int k = 0; k < DIN; ++k) {
            float4 a4 = *(const float4*)(avecF + (k << 2));
            float w  = W_init[(size_t)k * HD + j];
            acc0 = fmaf(a4.x, w, acc0);
            acc1 = fmaf(a4.y, w, acc1);
            acc2 = fmaf(a4.z, w, acc2);
            acc3 = fmaf(a4.w, w, acc3);
        }
        float bi = b_init[j];
        float y0v[RPB] = {acc0 + bi, acc1 + bi, acc2 + bi, acc3 + bi};
#pragma unroll
        for (int r = 0; r < RPB; ++r) {
            yF[r * HD + j] = y0v[r];
            pack4(y0v[r], catH, j, r);
            if (lidx_s[r] == 0) zfin[r * HD + j] = y0v[r];
        }
    }
    __syncthreads();

    // ---- decode y0 ----
    dec4(W_dec_2, b_dec, catH, part, j, b0, 0, out);

    // ---- main scan ----
    for (int t = 0; t < TT - 1; ++t) {
        // a_t (first 64 of 256-wide coeff row) for 4 rows, packed to half2
        if (j < 128) {
            int r = j & 3, kp = j >> 2;
            float2 a2 = *(const float2*)(coeffs +
                ((size_t)(b0 + r) * (TT - 1) + t) * (4 * DIN) + 2 * kp);
            __half2 hp = __floats2half2_rn(a2.x, a2.y);
            avecH[(kp << 2) + r] = __builtin_bit_cast(unsigned, hp);
        }
        __syncthreads();   // also closes dec4's part-read phase
        // xw = a_t @ W_X + b_X  -> catH xw half
        mv4<DIN / 2>(W_X_2, avecH, part, j);
        __syncthreads();
#pragma unroll
        for (int r = 0; r < RPB; ++r)
            pack4(red4(part, b_X, j, r), catH + 1024, j, r);
        __syncthreads();
        // z1 = [y,xw] @ W_emb + b_emb -> actAH
        mv4<HD>(W_emb_2, catH, part, j);
        __syncthreads();
#pragma unroll
        for (int r = 0; r < RPB; ++r)
            pack4(red4(part, b_emb, j, r), actAH, j, r);
        __syncthreads();
        // z2 = lipswish(z1 @ Wf1 + bf1) -> actBH
        mv4<HD / 2>(Wf1_2, actAH, part, j);
        __syncthreads();
#pragma unroll
        for (int r = 0; r < RPB; ++r)
            pack4(lipswish(red4(part, bf1, j, r)), actBH, j, r);
        __syncthreads();
        // z3 = z2 @ Wf2 + bf2 -> actAH
        mv4<HD / 2>(Wf2_2, actBH, part, j);
        __syncthreads();
#pragma unroll
        for (int r = 0; r < RPB; ++r)
            pack4(red4(part, bf2, j, r), actAH, j, r);
        __syncthreads();
        // drift = z3 @ W_out + b_out; Euler update -> yF, catH y half
        mv4<HD / 2>(W_out_2, actAH, part, j);
        __syncthreads();
        {
            float dtv = tl[t + 1] - tl[t];
            float gv  = gs[(size_t)t * HD + j];
#pragma unroll
            for (int r = 0; r < RPB; ++r) {
                float dr = red4(part, b_out, j, r);
                float yn = yF[r * HD + j] + dr * dtv
                         + gv * noise[((size_t)t * BB + b0 + r) * HD + j];
                yF[r * HD + j] = yn;
                pack4(yn, catH, j, r);
                if (t + 1 == lidx_s[r]) zfin[r * HD + j] = yn;
            }
        }
        __syncthreads();
        // decode y_{t+1}
        dec4(W_dec_2, b_dec, catH, part, j, b0, t + 1, out);
    }
    __syncthreads();

    // ---- logits (fp32, one-time, per row) ----
    for (int r = 0; r < RPB; ++r) {
        int c = j & 15, seg = j >> 4;
        float p = 0.f;
        if (c < NCLS) {
#pragma unroll
            for (int k = seg * 16; k < seg * 16 + 16; ++k)
                p = fmaf(zfin[r * HD + k], W_cls[k * NCLS + c], p);
        }
        part[j] = p;
        __syncthreads();
        if (j < NCLS) {
            float s = b_cls[j];
#pragma unroll
            for (int sg = 0; sg < 32; ++sg) s += part[sg * 16 + j];
            out[(size_t)BB * TT * DOUT + (size_t)(b0 + r) * NCLS + j] = s;
        }
        __syncthreads();
    }
}

extern "C" void kernel_launch(void* const* d_in, const int* in_sizes, int n_in,
                              void* d_out, int out_size, void* d_ws, size_t ws_size,
                              hipStream_t stream)
{
    const float* coeffs  = (const float*)d_in[0];
    const float* times   = (const float*)d_in[1];
    const float* noise   = (const float*)d_in[2];
    const float* W_X     = (const float*)d_in[3];
    const float* b_X     = (const float*)d_in[4];
    const float* W_emb   = (const float*)d_in[5];
    const float* b_emb   = (const float*)d_in[6];
    const float* Wf1     = (const float*)d_in[7];
    const float* bf1     = (const float*)d_in[8];
    const float* Wf2     = (const float*)d_in[9];
    const float* bf2     = (const float*)d_in[10];
    const float* W_out   = (const float*)d_in[11];
    const float* b_out   = (const float*)d_in[12];
    const float* W_noise = (const float*)d_in[13];
    const float* b_noise = (const float*)d_in[14];
    const float* Wg1     = (const float*)d_in[15];
    const float* bg1     = (const float*)d_in[16];
    const float* Wg2     = (const float*)d_in[17];
    const float* bg2     = (const float*)d_in[18];
    const float* W_init  = (const float*)d_in[19];
    const float* b_init  = (const float*)d_in[20];
    const float* W_dec   = (const float*)d_in[21];
    const float* b_dec   = (const float*)d_in[22];
    const float* W_cls   = (const float*)d_in[23];
    const float* b_cls   = (const float*)d_in[24];
    const int*   mask    = (const int*)d_in[25];

    float*    gs = (float*)d_ws;
    unsigned* W2 = (unsigned*)((char*)d_ws + GS_BYTES);
    float*   out = (float*)d_out;

    cvt_kernel<<<dim3(NPACK / 512), dim3(512), 0, stream>>>(
        W_X, W_emb, Wf1, Wf2, W_out, W_dec, W2);

    g_kernel<<<dim3(TT - 1), dim3(HD), 0, stream>>>(
        times, W_noise, b_noise, Wg1, bg1, Wg2, bg2, gs);

    scan_kernel<<<dim3(BB / RPB), dim3(512), 0, stream>>>(
        coeffs, times, noise, b_X, b_emb, bf1, bf2, b_out,
        W_init, b_init, b_dec, W_cls, b_cls, mask, gs, W2, out);
}